// Round 9
// baseline (143.734 us; speedup 1.0000x reference)
//
#include <hip/hip_runtime.h>

#define B_ 128
#define O_ 1024
#define I_ 1024
#define NCHUNK 64
#define CI (I_ / NCHUNK)     // 16 i-values per wave
#define WPB 4                // waves per block
#define TT_BYTES ((size_t)O_ * I_ * sizeof(float))

#define LOG2E_F  1.4426950408889634f
#define LN2_F    0.6931471805599453f
#define LN2SQ_F  0.4804530139182014f          // ln2^2
#define EPSC_F   (1e-7f * LN2SQ_F)            // eps * ln2^2

typedef float v2f __attribute__((ext_vector_type(2)));

__device__ __forceinline__ float fast_rsq(float x)  { return __builtin_amdgcn_rsqf(x); }
__device__ __forceinline__ float fast_exp2(float x) { return __builtin_amdgcn_exp2f(x); }
__device__ __forceinline__ float fast_rcp(float x)  { return __builtin_amdgcn_rcpf(x); }

__device__ __forceinline__ float rfl(float x) {
    return __builtin_bit_cast(float,
        __builtin_amdgcn_readfirstlane(__builtin_bit_cast(int, x)));
}

template <int CTRL>
__device__ __forceinline__ float dpp_add(float v) {
    int x = __builtin_amdgcn_update_dpp(0, __builtin_bit_cast(int, v),
                                        CTRL, 0xf, 0xf, true);
    return v + __builtin_bit_cast(float, x);
}
// 64-lane sum -> SGPR-uniform
__device__ __forceinline__ float wave_sum_uniform(float v) {
    v = dpp_add<0xB1>(v);   // quad_perm [1,0,3,2]
    v = dpp_add<0x4E>(v);   // quad_perm [2,3,0,1]
    v = dpp_add<0x141>(v);  // row_half_mirror
    v = dpp_add<0x140>(v);  // row_mirror
    v = dpp_add<0x142>(v);  // row_bcast15
    v = dpp_add<0x143>(v);  // row_bcast31
    return __builtin_bit_cast(float,
        __builtin_amdgcn_readlane(__builtin_bit_cast(int, v), 63));
}

// ---------------------------------------------------------------------------
// Kernel 1 (exact): Tt2[i*O+o] = T[o,i]^2 transposed; per-i min of T^2 via
// bitwise atomicMin (float bits monotone for >=0); d_out zeroing folded in.
// ---------------------------------------------------------------------------
__global__ __launch_bounds__(256) void build_T2_kernel(
    const float* __restrict__ ix, const float* __restrict__ iy,
    const float* __restrict__ ox, const float* __restrict__ oy,
    const float* __restrict__ la, const float* __restrict__ lm,
    float* __restrict__ Tt2, unsigned* __restrict__ minbits,
    float* __restrict__ out_zero)
{
    __shared__ float tile[32][33];
    __shared__ unsigned mloc[32];
    const int i0 = blockIdx.x * 32;
    const int o0 = blockIdx.y * 32;
    const int tx = threadIdx.x;      // 0..31
    const int ty = threadIdx.y;      // 0..7
    const int t  = ty * 32 + tx;     // 0..255

    if (t < 32) mloc[t] = 0xFFFFFFFFu;

    const int bid = blockIdx.y * gridDim.x + blockIdx.x;   // 0..1023
    if (t < 128) out_zero[bid * 128 + t] = 0.0f;

#pragma unroll
    for (int r = 0; r < 32; r += 8) {
        const int o = o0 + ty + r;
        const int i = i0 + tx;
        const int idx = o * I_ + i;
        const float tt = fmaf(ix[idx] * fast_rcp(iy[idx]) + la[idx],
                              1.0f + lm[idx],
                              -(ox[idx] * fast_rcp(oy[idx])));
        tile[ty + r][tx] = tt * tt;
    }
    __syncthreads();
#pragma unroll
    for (int r = 0; r < 32; r += 8) {
        const int i = i0 + ty + r;
        const int o = o0 + tx;
        Tt2[i * O_ + o] = tile[tx][ty + r];
    }
    const int il = t & 31;
    const int g  = t >> 5;
    float mn = fminf(fminf(tile[4 * g + 0][il], tile[4 * g + 1][il]),
                     fminf(tile[4 * g + 2][il], tile[4 * g + 3][il]));
    atomicMin(&mloc[il], __builtin_bit_cast(unsigned, mn));
    __syncthreads();
    if (t < 32) atomicMin(&minbits[i0 + t], mloc[t]);
}

// ---------------------------------------------------------------------------
// Kernel 2 (R6 exact math, VGPR-dieted to <=64 for the 8-waves/SIMD tier):
// wave owns 16 i's; lane owns 16 o's. e computed IN-PLACE over the row
// registers (no separate e array). Uniform per-i values in SGPRs. Single
// DPP z-reduce. launch_bounds(256,8) pins the allocator at 64 VGPR.
// ---------------------------------------------------------------------------
__global__ __launch_bounds__(256, 8) void aeg_main_kernel(
    const float* __restrict__ data,   // (B, I)
    const float* __restrict__ Tt2,    // (I, O) transposed T^2
    const float* __restrict__ minr2,  // (I) min T^2 (float bits)
    float* __restrict__ out)          // (B, O), zeroed by build_T2
{
    __shared__ float red[WPB][O_];    // 16 KB

    const int w    = threadIdx.x >> 6;
    const int lane = threadIdx.x & 63;
    const int chunk = blockIdx.x * WPB + w;
    const int b     = blockIdx.y;

    const float4* rowbase = (const float4*)(Tt2 + (size_t)chunk * CI * O_);

    // ---- prologue: all wave-uniform per-i values into SGPRs ----
    const float4* dv4 = (const float4*)(data + b * I_ + chunk * CI);
    const float4* mr4 = (const float4*)(minr2 + chunk * CI);
    float sdv[CI], ss2[CI], sm2[CI];
#pragma unroll
    for (int k = 0; k < 4; ++k) {
        const float4 a = dv4[k];
        const float4 m = mr4[k];
        const float av[4] = {a.x, a.y, a.z, a.w};
        const float mv[4] = {m.x, m.y, m.z, m.w};
#pragma unroll
        for (int j = 0; j < 4; ++j) {
            const float dv  = av[j];
            const float sig = fast_rcp(1.0f + fast_exp2(-dv * LOG2E_F));
            const float sc  = sig * LN2_F;
            const float s2  = sc * sc;
            const float m2  = fast_rsq(fmaf(mv[j], s2, EPSC_F)); // exact max
            sdv[4 * k + j] = rfl(dv);
            ss2[4 * k + j] = rfl(s2);
            sm2[4 * k + j] = rfl(m2);
        }
    }

    v2f acc2[8];
#pragma unroll
    for (int j = 0; j < 8; ++j) acc2[j] = (v2f)0.0f;

    float4 rr[2][4];
#pragma unroll
    for (int k = 0; k < 4; ++k) rr[0][k] = rowbase[lane + 64 * k];

#pragma unroll
    for (int ii = 0; ii < CI; ++ii) {
        if (ii + 1 < CI) {
            const float4* nrow = rowbase + (size_t)(ii + 1) * (O_ / 4);
#pragma unroll
            for (int k = 0; k < 4; ++k) rr[(ii + 1) & 1][k] = nrow[lane + 64 * k];
        }
        float4* r = rr[ii & 1];
        const v2f s2v = {ss2[ii], ss2[ii]};
        const v2f m2v = {sm2[ii], sm2[ii]};
        const v2f epv = {EPSC_F, EPSC_F};

        v2f zv0 = (v2f)0.0f, zv1 = (v2f)0.0f;
#pragma unroll
        for (int k = 0; k < 4; ++k) {
            const v2f a = {r[k].x, r[k].y};
            const v2f c = {r[k].z, r[k].w};
            const v2f q0 = a * s2v + epv;                  // pk_fma
            const v2f q1 = c * s2v + epv;
            v2f t0, t1;
            t0.x = fast_rsq(q0.x); t0.y = fast_rsq(q0.y);
            t1.x = fast_rsq(q1.x); t1.y = fast_rsq(q1.y);
            t0 -= m2v;                                     // pk_add
            t1 -= m2v;
            // e overwrites the row registers (r dead after this)
            r[k].x = fast_exp2(t0.x); r[k].y = fast_exp2(t0.y);
            r[k].z = fast_exp2(t1.x); r[k].w = fast_exp2(t1.y);
            zv0 += (v2f){r[k].x, r[k].y};
            zv1 += (v2f){r[k].z, r[k].w};
        }
        const v2f zv = zv0 + zv1;
        const float zt = wave_sum_uniform(zv.x + zv.y);    // SGPR-uniform
        const float scale = sdv[ii] * fast_rcp(zt);        // z >= 1
        const v2f sc2 = {scale, scale};
#pragma unroll
        for (int k = 0; k < 4; ++k) {
            acc2[2 * k]     = (v2f){r[k].x, r[k].y} * sc2 + acc2[2 * k];
            acc2[2 * k + 1] = (v2f){r[k].z, r[k].w} * sc2 + acc2[2 * k + 1];
        }
    }

    // Cross-wave LDS reduce (quarters the atomic count), then atomics.
#pragma unroll
    for (int k = 0; k < 4; ++k) {
        float4 v;
        v.x = acc2[2 * k].x;     v.y = acc2[2 * k].y;
        v.z = acc2[2 * k + 1].x; v.w = acc2[2 * k + 1].y;
        ((float4*)&red[w][256 * k])[lane] = v;
    }
    __syncthreads();

    const int t = threadIdx.x;
    float4 v = ((const float4*)red[0])[t];
#pragma unroll
    for (int ww = 1; ww < WPB; ++ww) {
        const float4 u = ((const float4*)red[ww])[t];
        v.x += u.x; v.y += u.y; v.z += u.z; v.w += u.w;
    }
    float* ob = out + b * O_ + 4 * t;
    atomicAdd(&ob[0], v.x);
    atomicAdd(&ob[1], v.y);
    atomicAdd(&ob[2], v.z);
    atomicAdd(&ob[3], v.w);
}

// ---------------------------------------------------------------------------
extern "C" void kernel_launch(void* const* d_in, const int* in_sizes, int n_in,
                              void* d_out, int out_size, void* d_ws, size_t ws_size,
                              hipStream_t stream)
{
    const float* data = (const float*)d_in[0];
    const float* ix   = (const float*)d_in[1];
    const float* iy   = (const float*)d_in[2];
    const float* ox   = (const float*)d_in[3];
    const float* oy   = (const float*)d_in[4];
    const float* la   = (const float*)d_in[5];
    const float* lm   = (const float*)d_in[6];
    float* out  = (float*)d_out;
    float* Tt2  = (float*)d_ws;
    unsigned* minbits = (unsigned*)((char*)d_ws + TT_BYTES);

    (void)hipMemsetAsync(minbits, 0xFF, I_ * sizeof(unsigned), stream);

    build_T2_kernel<<<dim3(I_ / 32, O_ / 32), dim3(32, 8), 0, stream>>>(
        ix, iy, ox, oy, la, lm, Tt2, minbits, out);

    aeg_main_kernel<<<dim3(NCHUNK / WPB, B_), 256, 0, stream>>>(
        data, Tt2, (const float*)minbits, out);
}

// Round 10
// 121.968 us; speedup vs baseline: 1.1785x; 1.1785x over previous
//
#include <hip/hip_runtime.h>

#define B_ 128
#define O_ 1024
#define I_ 1024
#define NCHUNK 64
#define CI (I_ / NCHUNK)     // 16 i-values per wave
#define WPB 4                // waves per block
#define TT_BYTES ((size_t)O_ * I_ * sizeof(float))

#define LOG2E_F  1.4426950408889634f
#define LN2_F    0.6931471805599453f
#define LN2SQ_F  0.4804530139182014f          // ln2^2
#define EPSC_F   (1e-7f * LN2SQ_F)            // eps * ln2^2

typedef float v2f __attribute__((ext_vector_type(2)));

__device__ __forceinline__ float fast_rsq(float x)  { return __builtin_amdgcn_rsqf(x); }
__device__ __forceinline__ float fast_exp2(float x) { return __builtin_amdgcn_exp2f(x); }
__device__ __forceinline__ float fast_rcp(float x)  { return __builtin_amdgcn_rcpf(x); }

__device__ __forceinline__ float rfl(float x) {
    return __builtin_bit_cast(float,
        __builtin_amdgcn_readfirstlane(__builtin_bit_cast(int, x)));
}

template <int CTRL>
__device__ __forceinline__ float dpp_add(float v) {
    int x = __builtin_amdgcn_update_dpp(0, __builtin_bit_cast(int, v),
                                        CTRL, 0xf, 0xf, true);
    return v + __builtin_bit_cast(float, x);
}
// 64-lane sum -> SGPR-uniform
__device__ __forceinline__ float wave_sum_uniform(float v) {
    v = dpp_add<0xB1>(v);   // quad_perm [1,0,3,2]
    v = dpp_add<0x4E>(v);   // quad_perm [2,3,0,1]
    v = dpp_add<0x141>(v);  // row_half_mirror
    v = dpp_add<0x140>(v);  // row_mirror
    v = dpp_add<0x142>(v);  // row_bcast15
    v = dpp_add<0x143>(v);  // row_bcast31
    return __builtin_bit_cast(float,
        __builtin_amdgcn_readlane(__builtin_bit_cast(int, v), 63));
}

// ---------------------------------------------------------------------------
// Kernel 1 (exact): Tt2[i*O+o] = T[o,i]^2 transposed; per-i min of T^2 via
// bitwise atomicMin (float bits monotone for >=0); d_out zeroing folded in.
// ---------------------------------------------------------------------------
__global__ __launch_bounds__(256) void build_T2_kernel(
    const float* __restrict__ ix, const float* __restrict__ iy,
    const float* __restrict__ ox, const float* __restrict__ oy,
    const float* __restrict__ la, const float* __restrict__ lm,
    float* __restrict__ Tt2, unsigned* __restrict__ minbits,
    float* __restrict__ out_zero)
{
    __shared__ float tile[32][33];
    __shared__ unsigned mloc[32];
    const int i0 = blockIdx.x * 32;
    const int o0 = blockIdx.y * 32;
    const int tx = threadIdx.x;      // 0..31
    const int ty = threadIdx.y;      // 0..7
    const int t  = ty * 32 + tx;     // 0..255

    if (t < 32) mloc[t] = 0xFFFFFFFFu;

    const int bid = blockIdx.y * gridDim.x + blockIdx.x;   // 0..1023
    if (t < 128) out_zero[bid * 128 + t] = 0.0f;

#pragma unroll
    for (int r = 0; r < 32; r += 8) {
        const int o = o0 + ty + r;
        const int i = i0 + tx;
        const int idx = o * I_ + i;
        const float tt = fmaf(ix[idx] * fast_rcp(iy[idx]) + la[idx],
                              1.0f + lm[idx],
                              -(ox[idx] * fast_rcp(oy[idx])));
        tile[ty + r][tx] = tt * tt;
    }
    __syncthreads();
#pragma unroll
    for (int r = 0; r < 32; r += 8) {
        const int i = i0 + ty + r;
        const int o = o0 + tx;
        Tt2[i * O_ + o] = tile[tx][ty + r];
    }
    const int il = t & 31;
    const int g  = t >> 5;
    float mn = fminf(fminf(tile[4 * g + 0][il], tile[4 * g + 1][il]),
                     fminf(tile[4 * g + 2][il], tile[4 * g + 3][il]));
    atomicMin(&mloc[il], __builtin_bit_cast(unsigned, mn));
    __syncthreads();
    if (t < 32) atomicMin(&minbits[i0 + t], mloc[t]);
}

// ---------------------------------------------------------------------------
// Kernel 2 (R6 exact math; register-dieted WITHOUT any forced wave bound —
// R9's __launch_bounds__(256,8) caused catastrophic scratch spill): e is
// computed IN-PLACE over the dying row registers, removing the separate
// 16-reg e-array from the live set. Uniform per-i values in SGPRs; single
// DPP z-reduce; ping-pong row prefetch; cross-wave LDS reduce.
// ---------------------------------------------------------------------------
__global__ __launch_bounds__(256) void aeg_main_kernel(
    const float* __restrict__ data,   // (B, I)
    const float* __restrict__ Tt2,    // (I, O) transposed T^2
    const float* __restrict__ minr2,  // (I) min T^2 (float bits)
    float* __restrict__ out)          // (B, O), zeroed by build_T2
{
    __shared__ float red[WPB][O_];    // 16 KB

    const int w    = threadIdx.x >> 6;
    const int lane = threadIdx.x & 63;
    const int chunk = blockIdx.x * WPB + w;
    const int b     = blockIdx.y;

    const float4* rowbase = (const float4*)(Tt2 + (size_t)chunk * CI * O_);

    // ---- prologue: all wave-uniform per-i values into SGPRs ----
    const float4* dv4 = (const float4*)(data + b * I_ + chunk * CI);
    const float4* mr4 = (const float4*)(minr2 + chunk * CI);
    float sdv[CI], ss2[CI], sm2[CI];
#pragma unroll
    for (int k = 0; k < 4; ++k) {
        const float4 a = dv4[k];
        const float4 m = mr4[k];
        const float av[4] = {a.x, a.y, a.z, a.w};
        const float mv[4] = {m.x, m.y, m.z, m.w};
#pragma unroll
        for (int j = 0; j < 4; ++j) {
            const float dv  = av[j];
            const float sig = fast_rcp(1.0f + fast_exp2(-dv * LOG2E_F));
            const float sc  = sig * LN2_F;
            const float s2  = sc * sc;
            const float m2  = fast_rsq(fmaf(mv[j], s2, EPSC_F)); // exact max
            sdv[4 * k + j] = rfl(dv);
            ss2[4 * k + j] = rfl(s2);
            sm2[4 * k + j] = rfl(m2);
        }
    }

    v2f acc2[8];
#pragma unroll
    for (int j = 0; j < 8; ++j) acc2[j] = (v2f)0.0f;

    float4 rr[2][4];
#pragma unroll
    for (int k = 0; k < 4; ++k) rr[0][k] = rowbase[lane + 64 * k];

#pragma unroll
    for (int ii = 0; ii < CI; ++ii) {
        if (ii + 1 < CI) {
            const float4* nrow = rowbase + (size_t)(ii + 1) * (O_ / 4);
#pragma unroll
            for (int k = 0; k < 4; ++k) rr[(ii + 1) & 1][k] = nrow[lane + 64 * k];
        }
        float4* r = rr[ii & 1];
        const v2f s2v = {ss2[ii], ss2[ii]};
        const v2f m2v = {sm2[ii], sm2[ii]};
        const v2f epv = {EPSC_F, EPSC_F};

        v2f zv0 = (v2f)0.0f, zv1 = (v2f)0.0f;
#pragma unroll
        for (int k = 0; k < 4; ++k) {
            const v2f a = {r[k].x, r[k].y};
            const v2f c = {r[k].z, r[k].w};
            const v2f q0 = a * s2v + epv;                  // pk_fma
            const v2f q1 = c * s2v + epv;
            v2f t0, t1;
            t0.x = fast_rsq(q0.x); t0.y = fast_rsq(q0.y);
            t1.x = fast_rsq(q1.x); t1.y = fast_rsq(q1.y);
            t0 -= m2v;                                     // pk_add
            t1 -= m2v;
            // e overwrites the row registers (row value dead after q)
            r[k].x = fast_exp2(t0.x); r[k].y = fast_exp2(t0.y);
            r[k].z = fast_exp2(t1.x); r[k].w = fast_exp2(t1.y);
            zv0 += (v2f){r[k].x, r[k].y};
            zv1 += (v2f){r[k].z, r[k].w};
        }
        const v2f zv = zv0 + zv1;
        const float zt = wave_sum_uniform(zv.x + zv.y);    // SGPR-uniform
        const float scale = sdv[ii] * fast_rcp(zt);        // z >= 1
        const v2f sc2 = {scale, scale};
#pragma unroll
        for (int k = 0; k < 4; ++k) {
            acc2[2 * k]     = (v2f){r[k].x, r[k].y} * sc2 + acc2[2 * k];
            acc2[2 * k + 1] = (v2f){r[k].z, r[k].w} * sc2 + acc2[2 * k + 1];
        }
    }

    // Cross-wave LDS reduce (quarters the atomic count), then atomics.
#pragma unroll
    for (int k = 0; k < 4; ++k) {
        float4 v;
        v.x = acc2[2 * k].x;     v.y = acc2[2 * k].y;
        v.z = acc2[2 * k + 1].x; v.w = acc2[2 * k + 1].y;
        ((float4*)&red[w][256 * k])[lane] = v;
    }
    __syncthreads();

    const int t = threadIdx.x;
    float4 v = ((const float4*)red[0])[t];
#pragma unroll
    for (int ww = 1; ww < WPB; ++ww) {
        const float4 u = ((const float4*)red[ww])[t];
        v.x += u.x; v.y += u.y; v.z += u.z; v.w += u.w;
    }
    float* ob = out + b * O_ + 4 * t;
    atomicAdd(&ob[0], v.x);
    atomicAdd(&ob[1], v.y);
    atomicAdd(&ob[2], v.z);
    atomicAdd(&ob[3], v.w);
}

// ---------------------------------------------------------------------------
extern "C" void kernel_launch(void* const* d_in, const int* in_sizes, int n_in,
                              void* d_out, int out_size, void* d_ws, size_t ws_size,
                              hipStream_t stream)
{
    const float* data = (const float*)d_in[0];
    const float* ix   = (const float*)d_in[1];
    const float* iy   = (const float*)d_in[2];
    const float* ox   = (const float*)d_in[3];
    const float* oy   = (const float*)d_in[4];
    const float* la   = (const float*)d_in[5];
    const float* lm   = (const float*)d_in[6];
    float* out  = (float*)d_out;
    float* Tt2  = (float*)d_ws;
    unsigned* minbits = (unsigned*)((char*)d_ws + TT_BYTES);

    (void)hipMemsetAsync(minbits, 0xFF, I_ * sizeof(unsigned), stream);

    build_T2_kernel<<<dim3(I_ / 32, O_ / 32), dim3(32, 8), 0, stream>>>(
        ix, iy, ox, oy, la, lm, Tt2, minbits, out);

    aeg_main_kernel<<<dim3(NCHUNK / WPB, B_), 256, 0, stream>>>(
        data, Tt2, (const float*)minbits, out);
}